// Round 12
// baseline (4469.368 us; speedup 1.0000x reference)
//
#include <hip/hip_runtime.h>

// Bidirectional GRU, persistent-kernel. Round 12.
// Real work (blocks 0-63): r11 VERBATIM - best measured (4.42ms), proven
// protocol (agent-relaxed sc0sc1 comm, all-wave publish, per-wave h-drain,
// monotonic flags, lgkm-only barriers, prefetch issued post-flag).
// ROUND 12 MECHANISM (one change): HEATER BLOCKS 64-255. The chip runs at
// ~2% VALUBusy -> DPM drops SCLK; every serial-chain term (compute, issue,
// part of fabric RTT) scales with clock. Heaters burn dependent FMA chains
// (no memory traffic) to pin utilization ~70% -> governor boosts SCLK.
// Liveness: heaters exit when done-counter reaches 64 (posted by each real
// WG after its last step); hard iteration budget as backstop -> no hang.

#define T_LEN 1024
#define B_SZ  32
#define D_SZ  512
#define H_SZ  512
#define NWG_DIR 32
#define JW 16
#define NTHR 512

typedef __attribute__((ext_vector_type(8))) _Float16 half8;
typedef __attribute__((ext_vector_type(4))) float f32x4;
typedef __attribute__((ext_vector_type(4))) int int4v;

__device__ __forceinline__ _Float16 f2h(float f) { return (_Float16)f; }
__device__ __forceinline__ float sigm_f(float v) {
  return __builtin_amdgcn_rcpf(1.f + __expf(-v));
}
__device__ __forceinline__ float tanh_f(float v) {
  return 1.f - 2.f * __builtin_amdgcn_rcpf(1.f + __expf(2.f * v));
}
// LDS-only barrier: orders ds ops; does NOT drain vmcnt.
__device__ __forceinline__ void bar_lgkm() {
  asm volatile("s_waitcnt lgkmcnt(0)\ns_barrier" ::: "memory");
}

__global__ __launch_bounds__(NTHR, 2)
void gru2_persistent(const float* __restrict__ x,
                     const float* __restrict__ wih_fw, const float* __restrict__ whh_fw,
                     const float* __restrict__ bih_fw, const float* __restrict__ bhh_fw,
                     const float* __restrict__ wih_bw, const float* __restrict__ whh_bw,
                     const float* __restrict__ bih_bw, const float* __restrict__ bhh_bw,
                     float* __restrict__ out,
                     unsigned* __restrict__ hexu,
                     unsigned* __restrict__ flags,
                     unsigned* __restrict__ done)
{
  __shared__ float Cp[24 * 272];   // 24 C-partial tiles 16x16, +1 col pad
  __shared__ float biasLds[96];
  __shared__ volatile int hdone;   // heater-exit token (heater blocks only)

  const int bid  = blockIdx.x;
  const int tid  = threadIdx.x;
  const int wave = tid >> 6;
  const int lane = tid & 63;

  // ================= HEATER BLOCKS (64..255) =================
  if (bid >= 64) {
    if (tid == 0) hdone = 0;
    __syncthreads();
    float a0 = 1.1f + (float)lane, a1 = 2.2f + (float)wave;
    float a2 = 3.3f, a3 = 4.4f;
    // budget: 1<<18 outer x 1024 FMA ~ 0.5-1e9 cy max (backstop; normal exit
    // via done-counter). Zero memory traffic except 1 done-load / ~8us / block.
    for (int it = 0; it < (1 << 18); ++it) {
      #pragma unroll
      for (int j = 0; j < 256; ++j) {
        a0 = __builtin_fmaf(a0, 1.0000001f, 1e-9f);
        a1 = __builtin_fmaf(a1, 0.9999999f, 1e-9f);
        a2 = __builtin_fmaf(a2, 1.0000002f, 1e-9f);
        a3 = __builtin_fmaf(a3, 0.9999998f, 1e-9f);
      }
      if (tid == 0 && (it & 3) == 0) {
        unsigned d = __hip_atomic_load(done, __ATOMIC_RELAXED,
                                       __HIP_MEMORY_SCOPE_AGENT);
        if (d >= 64u) hdone = 1;
      }
      if (hdone) break;
    }
    asm volatile("" :: "v"(a0), "v"(a1), "v"(a2), "v"(a3));  // no-DCE sink
    return;
  }

  // ================= REAL WORK (blocks 0..63): r11 verbatim =================
  const int dir  = bid >> 5;      // 0 = fw, 1 = bw
  const int g    = bid & 31;      // slice: h-cols [g*16, g*16+16)

  const float* wih = dir ? wih_bw : wih_fw;
  const float* whh = dir ? whh_bw : whh_fw;
  const float* bih = dir ? bih_bw : bih_fw;
  const float* bhh = dir ? bhh_bw : bhh_fw;

  if (tid < 48) {
    int grow = (tid >> 4) * H_SZ + g * JW + (tid & 15);
    biasLds[tid]      = bih[grow];
    biasLds[48 + tid] = bhh[grow];
  }

  const bool isHh = (wave >= 4);
  const int  wv   = wave & 3;
  const int  wm   = wv & 1;       // batch m-tile (16 rows)
  const int  kh   = wv >> 1;      // K half

  // ---- weight B-fragments in registers (layout proven r1-r11) ----
  half8 Bf[3][8];
  {
    const float* W = isHh ? whh : wih;
    #pragma unroll
    for (int gam = 0; gam < 3; ++gam) {
      const int row = gam * H_SZ + g * JW + (lane & 15);
      #pragma unroll
      for (int i = 0; i < 8; ++i) {
        const float* src = W + (size_t)row * D_SZ + (kh * 8 + i) * 32 + ((lane >> 4) << 3);
        float4 v0 = *(const float4*)(src);
        float4 v1 = *(const float4*)(src + 4);
        half8 b;
        b[0]=f2h(v0.x); b[1]=f2h(v0.y); b[2]=f2h(v0.z); b[3]=f2h(v0.w);
        b[4]=f2h(v1.x); b[5]=f2h(v1.y); b[6]=f2h(v1.z); b[7]=f2h(v1.w);
        Bf[gam][i] = b;
      }
    }
  }

  const int arow = wm * 16 + (lane & 15);   // batch row
  const int koff = (lane >> 4) << 3;        // k offset within 32-chunk
  const float* const xwavebase = x + (size_t)arow * T_LEN * D_SZ + kh * 256 + koff;

  // ---- ih prologue: x(t0) into registers
  float4 xn[16];
  if (!isHh) {
    const int t0 = dir ? (T_LEN - 1) : 0;
    const float* base = xwavebase + (size_t)t0 * D_SZ;
    #pragma unroll
    for (int i = 0; i < 8; ++i) {
      xn[2*i]   = *(const float4*)(base + i * 32);
      xn[2*i+1] = *(const float4*)(base + i * 32 + 4);
    }
  }
  __syncthreads();

  float hreg = 0.f;
  const int gb = tid >> 4;       // gate batch row
  const int gj = tid & 15;       // gate col within slice
  float* hlast = out + (size_t)B_SZ * T_LEN * (2 * H_SZ) + (size_t)dir * B_SZ * H_SZ;
  const unsigned* flbase = flags + (size_t)dir * NWG_DIR;

  for (int s = 0; s < T_LEN; ++s) {
    const int t = dir ? (T_LEN - 1 - s) : s;
    const bool hasNext = (s + 1 < T_LEN);

    f32x4 acc[3] = {{0.f,0.f,0.f,0.f},{0.f,0.f,0.f,0.f},{0.f,0.f,0.f,0.f}};

    if (!isHh) {
      half8 a[8];
      #pragma unroll
      for (int i = 0; i < 8; ++i) {
        float4 u = xn[2*i], w = xn[2*i+1];
        half8 h;
        h[0]=f2h(u.x); h[1]=f2h(u.y); h[2]=f2h(u.z); h[3]=f2h(u.w);
        h[4]=f2h(w.x); h[5]=f2h(w.y); h[6]=f2h(w.z); h[7]=f2h(w.w);
        a[i] = h;
      }
      #pragma unroll
      for (int i = 0; i < 8; ++i)
        #pragma unroll
        for (int gam = 0; gam < 3; ++gam)
          acc[gam] = __builtin_amdgcn_mfma_f32_16x16x32_f16(a[i], Bf[gam][i], acc[gam], 0, 0, 0);
    } else if (s > 0) {
      // ---- flag poll (proven intrinsic loop; monotonic counters)
      for (;;) {
        unsigned v = (lane < NWG_DIR)
            ? __hip_atomic_load(&flbase[lane], __ATOMIC_RELAXED,
                                __HIP_MEMORY_SCOPE_AGENT)
            : 0xFFFFFFFFu;
        if (__all(v >= (unsigned)s)) break;
      }
      // ---- load h(s-1) payload exactly once (early-clobber asm, proven)
      const char* p0 = (const char*)hexu
          + (((size_t)dir * 2 + ((s - 1) & 1)) * (B_SZ * (H_SZ / 2))) * 4
          + (size_t)arow * (H_SZ * 2) + (size_t)(kh * 256 + koff) * 2;
      int4v hv[8];
      asm volatile(
        "global_load_dwordx4 %0, %8, off sc0 sc1\n\t"
        "global_load_dwordx4 %1, %8, off offset:64 sc0 sc1\n\t"
        "global_load_dwordx4 %2, %8, off offset:128 sc0 sc1\n\t"
        "global_load_dwordx4 %3, %8, off offset:192 sc0 sc1\n\t"
        "global_load_dwordx4 %4, %8, off offset:256 sc0 sc1\n\t"
        "global_load_dwordx4 %5, %8, off offset:320 sc0 sc1\n\t"
        "global_load_dwordx4 %6, %8, off offset:384 sc0 sc1\n\t"
        "global_load_dwordx4 %7, %8, off offset:448 sc0 sc1\n\t"
        "s_waitcnt vmcnt(0)"
        : "=&v"(hv[0]), "=&v"(hv[1]), "=&v"(hv[2]), "=&v"(hv[3]),
          "=&v"(hv[4]), "=&v"(hv[5]), "=&v"(hv[6]), "=&v"(hv[7])
        : "v"(p0) : "memory");
      __builtin_amdgcn_sched_barrier(0);
      #pragma unroll
      for (int i = 0; i < 8; ++i) {
        half8 a = __builtin_bit_cast(half8, hv[i]);
        #pragma unroll
        for (int gam = 0; gam < 3; ++gam)
          acc[gam] = __builtin_amdgcn_mfma_f32_16x16x32_f16(a, Bf[gam][i], acc[gam], 0, 0, 0);
      }
    }
    // hh at s==0: acc stays zero (h0 = 0)

    // ---- write C-partials
    {
      const int src = isHh ? 1 : 0;
      #pragma unroll
      for (int gam = 0; gam < 3; ++gam) {
        float* cp = Cp + (size_t)(((src*2 + kh)*3 + gam)*2 + wm) * 272
                       + ((lane >> 4) << 2) * 17 + (lane & 15);
        #pragma unroll
        for (int vv2 = 0; vv2 < 4; ++vv2) cp[vv2 * 17] = acc[gam][vv2];
      }
    }
    bar_lgkm();   // B1: Cp ready (lgkm only)

    // ---- gates (all 512 threads): compute h(s), publish h pair
    float hnS;
    {
      const int mb = gb >> 4, rb = gb & 15;
      float sih[3], shh[3];
      #pragma unroll
      for (int gam = 0; gam < 3; ++gam) {
        float aih = 0.f, ahh = 0.f;
        #pragma unroll
        for (int q = 0; q < 2; ++q) {
          aih += Cp[(size_t)(((0*2+q)*3+gam)*2 + mb) * 272 + rb * 17 + gj];
          ahh += Cp[(size_t)(((1*2+q)*3+gam)*2 + mb) * 272 + rb * 17 + gj];
        }
        sih[gam] = aih + biasLds[gam * 16 + gj];
        shh[gam] = ahh + biasLds[48 + gam * 16 + gj];
      }
      const float r = sigm_f(sih[0] + shh[0]);
      const float z = sigm_f(sih[1] + shh[1]);
      const float n = tanh_f(sih[2] + r * shh[2]);
      const float hn = (1.f - z) * n + z * hreg;
      hreg = hn;
      hnS = hn;

      const float hother = __shfl_xor(hn, 1);
      if ((gj & 1) == 0) {
        union { unsigned u; _Float16 h[2]; } pr;
        pr.h[0] = f2h(hn); pr.h[1] = f2h(hother);
        unsigned* hp = hexu + ((size_t)dir * 2 + (s & 1)) * (B_SZ * (H_SZ / 2))
                     + (size_t)gb * (H_SZ / 2) + (g * JW + gj) / 2;
        __hip_atomic_store(hp, pr.u, __ATOMIC_RELAXED, __HIP_MEMORY_SCOPE_AGENT);
      }
    }
    // per-wave drain: only this step's h-store (+ long-landed older stores)
    asm volatile("s_waitcnt vmcnt(0)" ::: "memory");
    bar_lgkm();   // B2: every wave has drained its h-store
    if (tid == 0)
      __hip_atomic_store((unsigned*)&flags[(size_t)dir * NWG_DIR + g],
                         (unsigned)(s + 1),
                         __ATOMIC_RELAXED, __HIP_MEMORY_SCOPE_AGENT);

    // ---- off-chain tail: out stores, then issue x(t+1) prefetch
    out[((size_t)gb * T_LEN + t) * (2 * H_SZ) + dir * H_SZ + g * JW + gj] = hnS;
    if (s == T_LEN - 1) hlast[gb * H_SZ + g * JW + gj] = hnS;
    if (!isHh && hasNext) {
      const int tn = dir ? (T_LEN - 2 - s) : (s + 1);
      const float* base = xwavebase + (size_t)tn * D_SZ;
      #pragma unroll
      for (int i = 0; i < 8; ++i) {
        xn[2*i]   = *(const float4*)(base + i * 32);
        xn[2*i+1] = *(const float4*)(base + i * 32 + 4);
      }
    }
  }

  // signal heaters: this real WG is finished
  if (tid == 0)
    __hip_atomic_fetch_add(done, 1u, __ATOMIC_RELAXED, __HIP_MEMORY_SCOPE_AGENT);
}

extern "C" void kernel_launch(void* const* d_in, const int* in_sizes, int n_in,
                              void* d_out, int out_size, void* d_ws, size_t ws_size,
                              hipStream_t stream) {
  const float* x      = (const float*)d_in[0];
  const float* wih_fw = (const float*)d_in[1];
  const float* whh_fw = (const float*)d_in[2];
  const float* bih_fw = (const float*)d_in[3];
  const float* bhh_fw = (const float*)d_in[4];
  const float* wih_bw = (const float*)d_in[5];
  const float* whh_bw = (const float*)d_in[6];
  const float* bih_bw = (const float*)d_in[7];
  const float* bhh_bw = (const float*)d_in[8];
  float* out = (float*)d_out;

  // ws layout: [0..255] flags u32[2][32]; [256..259] done u32; pad to 512;
  //            [512..] hexu [2 dir][2 parity][32 rows][256 u32 pairs] = 128 KB.
  const size_t CTRL_BYTES = 512;
  const size_t HEX_BYTES  = (size_t)2 * 2 * B_SZ * (H_SZ / 2) * sizeof(unsigned);
  if (ws_size < CTRL_BYTES + HEX_BYTES) return;

  unsigned* flags = (unsigned*)d_ws;
  unsigned* done  = (unsigned*)((char*)d_ws + 256);
  unsigned* hexu  = (unsigned*)((char*)d_ws + CTRL_BYTES);

  hipMemsetAsync(d_ws, 0, CTRL_BYTES, stream);
  gru2_persistent<<<dim3(256), dim3(NTHR), 0, stream>>>(
      x, wih_fw, whh_fw, bih_fw, bhh_fw, wih_bw, whh_bw, bih_bw, bhh_bw,
      out, hexu, flags, done);
}

// Round 13
// 4414.353 us; speedup vs baseline: 1.0125x; 1.0125x over previous
//
#include <hip/hip_runtime.h>

// Bidirectional GRU, persistent-kernel. Round 13.
// Base: r11 VERBATIM (best measured, 4.42ms). Heater test (r12) killed the
// clock hypothesis: VALUBusy 75% -> dur unchanged. Chain model (fits r3-r12):
// period = compute 0.55us + drain(1 RTT) + flag(0.5) + detect(1.5) +
// payload(1) with LLC RTT ~1.05us => 4.3us/step. The one soft term is
// detect=1.5 RTT (serial probes: issue->vmcnt(0)->check).
// r13, poll only (two changes):
//  1) 2-deep PIPELINED poll: two probes in flight, vmcnt(1) waits the older
//     while the newer flies -> a probe is always in flight when flags land;
//     detect 1.5 -> ~1.0 RTT.
//  2) Fan-in 16: consumer wave kh only needs its K-half's 16 producers
//     (g in [kh*16, kh*16+16)); their flags sit in one 64B line.
// Everything else r11-exact (protocol proven r3/r11).

#define T_LEN 1024
#define B_SZ  32
#define D_SZ  512
#define H_SZ  512
#define NWG_DIR 32
#define JW 16
#define NTHR 512

typedef __attribute__((ext_vector_type(8))) _Float16 half8;
typedef __attribute__((ext_vector_type(4))) float f32x4;
typedef __attribute__((ext_vector_type(4))) int int4v;

__device__ __forceinline__ _Float16 f2h(float f) { return (_Float16)f; }
__device__ __forceinline__ float sigm_f(float v) {
  return __builtin_amdgcn_rcpf(1.f + __expf(-v));
}
__device__ __forceinline__ float tanh_f(float v) {
  return 1.f - 2.f * __builtin_amdgcn_rcpf(1.f + __expf(2.f * v));
}
// LDS-only barrier: orders ds ops; does NOT drain vmcnt.
__device__ __forceinline__ void bar_lgkm() {
  asm volatile("s_waitcnt lgkmcnt(0)\ns_barrier" ::: "memory");
}

__global__ __launch_bounds__(NTHR, 2)
void gru2_persistent(const float* __restrict__ x,
                     const float* __restrict__ wih_fw, const float* __restrict__ whh_fw,
                     const float* __restrict__ bih_fw, const float* __restrict__ bhh_fw,
                     const float* __restrict__ wih_bw, const float* __restrict__ whh_bw,
                     const float* __restrict__ bih_bw, const float* __restrict__ bhh_bw,
                     float* __restrict__ out,
                     unsigned* __restrict__ hexu,
                     unsigned* __restrict__ flags)
{
  __shared__ float Cp[24 * 272];   // 24 C-partial tiles 16x16, +1 col pad
  __shared__ float biasLds[96];

  const int bid  = blockIdx.x;
  const int dir  = bid >> 5;      // 0 = fw, 1 = bw
  const int g    = bid & 31;      // slice: h-cols [g*16, g*16+16)
  const int tid  = threadIdx.x;
  const int wave = tid >> 6;
  const int lane = tid & 63;

  const float* wih = dir ? wih_bw : wih_fw;
  const float* whh = dir ? whh_bw : whh_fw;
  const float* bih = dir ? bih_bw : bih_fw;
  const float* bhh = dir ? bhh_bw : bhh_fw;

  if (tid < 48) {
    int grow = (tid >> 4) * H_SZ + g * JW + (tid & 15);
    biasLds[tid]      = bih[grow];
    biasLds[48 + tid] = bhh[grow];
  }

  const bool isHh = (wave >= 4);
  const int  wv   = wave & 3;
  const int  wm   = wv & 1;       // batch m-tile (16 rows)
  const int  kh   = wv >> 1;      // K half

  // ---- weight B-fragments in registers (layout proven r1-r12) ----
  half8 Bf[3][8];
  {
    const float* W = isHh ? whh : wih;
    #pragma unroll
    for (int gam = 0; gam < 3; ++gam) {
      const int row = gam * H_SZ + g * JW + (lane & 15);
      #pragma unroll
      for (int i = 0; i < 8; ++i) {
        const float* src = W + (size_t)row * D_SZ + (kh * 8 + i) * 32 + ((lane >> 4) << 3);
        float4 v0 = *(const float4*)(src);
        float4 v1 = *(const float4*)(src + 4);
        half8 b;
        b[0]=f2h(v0.x); b[1]=f2h(v0.y); b[2]=f2h(v0.z); b[3]=f2h(v0.w);
        b[4]=f2h(v1.x); b[5]=f2h(v1.y); b[6]=f2h(v1.z); b[7]=f2h(v1.w);
        Bf[gam][i] = b;
      }
    }
  }

  const int arow = wm * 16 + (lane & 15);   // batch row
  const int koff = (lane >> 4) << 3;        // k offset within 32-chunk
  const float* const xwavebase = x + (size_t)arow * T_LEN * D_SZ + kh * 256 + koff;

  // ---- ih prologue: x(t0) into registers
  float4 xn[16];
  if (!isHh) {
    const int t0 = dir ? (T_LEN - 1) : 0;
    const float* base = xwavebase + (size_t)t0 * D_SZ;
    #pragma unroll
    for (int i = 0; i < 8; ++i) {
      xn[2*i]   = *(const float4*)(base + i * 32);
      xn[2*i+1] = *(const float4*)(base + i * 32 + 4);
    }
  }
  __syncthreads();

  float hreg = 0.f;
  const int gb = tid >> 4;       // gate batch row
  const int gj = tid & 15;       // gate col within slice
  float* hlast = out + (size_t)B_SZ * T_LEN * (2 * H_SZ) + (size_t)dir * B_SZ * H_SZ;
  // fan-in-16 poll address: this wave's K-half producers, one 64B line.
  // lanes 16-63 duplicate lanes 0-15 (harmless; __all over duplicates).
  const unsigned* const fa = flags + (size_t)dir * NWG_DIR + kh * 16 + (lane & 15);

  for (int s = 0; s < T_LEN; ++s) {
    const int t = dir ? (T_LEN - 1 - s) : s;
    const bool hasNext = (s + 1 < T_LEN);

    f32x4 acc[3] = {{0.f,0.f,0.f,0.f},{0.f,0.f,0.f,0.f},{0.f,0.f,0.f,0.f}};

    if (!isHh) {
      half8 a[8];
      #pragma unroll
      for (int i = 0; i < 8; ++i) {
        float4 u = xn[2*i], w = xn[2*i+1];
        half8 h;
        h[0]=f2h(u.x); h[1]=f2h(u.y); h[2]=f2h(u.z); h[3]=f2h(u.w);
        h[4]=f2h(w.x); h[5]=f2h(w.y); h[6]=f2h(w.z); h[7]=f2h(w.w);
        a[i] = h;
      }
      #pragma unroll
      for (int i = 0; i < 8; ++i)
        #pragma unroll
        for (int gam = 0; gam < 3; ++gam)
          acc[gam] = __builtin_amdgcn_mfma_f32_16x16x32_f16(a[i], Bf[gam][i], acc[gam], 0, 0, 0);
    } else if (s > 0) {
      // ---- 2-deep pipelined flag poll (fan-in 16, probes always in flight)
      {
        unsigned va, vb;
        asm volatile("global_load_dword %0, %1, off sc0 sc1" : "=&v"(va) : "v"(fa));
        asm volatile("global_load_dword %0, %1, off sc0 sc1" : "=&v"(vb) : "v"(fa));
        for (;;) {
          asm volatile("s_waitcnt vmcnt(1)" ::: "memory");   // oldest (va) done
          if (__all(va >= (unsigned)s)) break;
          asm volatile("global_load_dword %0, %1, off sc0 sc1" : "=&v"(va) : "v"(fa));
          asm volatile("s_waitcnt vmcnt(1)" ::: "memory");   // oldest (vb) done
          if (__all(vb >= (unsigned)s)) break;
          asm volatile("global_load_dword %0, %1, off sc0 sc1" : "=&v"(vb) : "v"(fa));
        }
        asm volatile("s_waitcnt vmcnt(0)" ::: "memory");     // drain leftover probe
      }
      // ---- load h(s-1) payload exactly once (early-clobber asm, proven)
      const char* p0 = (const char*)hexu
          + (((size_t)dir * 2 + ((s - 1) & 1)) * (B_SZ * (H_SZ / 2))) * 4
          + (size_t)arow * (H_SZ * 2) + (size_t)(kh * 256 + koff) * 2;
      int4v hv[8];
      asm volatile(
        "global_load_dwordx4 %0, %8, off sc0 sc1\n\t"
        "global_load_dwordx4 %1, %8, off offset:64 sc0 sc1\n\t"
        "global_load_dwordx4 %2, %8, off offset:128 sc0 sc1\n\t"
        "global_load_dwordx4 %3, %8, off offset:192 sc0 sc1\n\t"
        "global_load_dwordx4 %4, %8, off offset:256 sc0 sc1\n\t"
        "global_load_dwordx4 %5, %8, off offset:320 sc0 sc1\n\t"
        "global_load_dwordx4 %6, %8, off offset:384 sc0 sc1\n\t"
        "global_load_dwordx4 %7, %8, off offset:448 sc0 sc1\n\t"
        "s_waitcnt vmcnt(0)"
        : "=&v"(hv[0]), "=&v"(hv[1]), "=&v"(hv[2]), "=&v"(hv[3]),
          "=&v"(hv[4]), "=&v"(hv[5]), "=&v"(hv[6]), "=&v"(hv[7])
        : "v"(p0) : "memory");
      __builtin_amdgcn_sched_barrier(0);
      #pragma unroll
      for (int i = 0; i < 8; ++i) {
        half8 a = __builtin_bit_cast(half8, hv[i]);
        #pragma unroll
        for (int gam = 0; gam < 3; ++gam)
          acc[gam] = __builtin_amdgcn_mfma_f32_16x16x32_f16(a, Bf[gam][i], acc[gam], 0, 0, 0);
      }
    }
    // hh at s==0: acc stays zero (h0 = 0)

    // ---- write C-partials
    {
      const int src = isHh ? 1 : 0;
      #pragma unroll
      for (int gam = 0; gam < 3; ++gam) {
        float* cp = Cp + (size_t)(((src*2 + kh)*3 + gam)*2 + wm) * 272
                       + ((lane >> 4) << 2) * 17 + (lane & 15);
        #pragma unroll
        for (int vv2 = 0; vv2 < 4; ++vv2) cp[vv2 * 17] = acc[gam][vv2];
      }
    }
    bar_lgkm();   // B1: Cp ready (lgkm only)

    // ---- gates (all 512 threads): compute h(s), publish h pair
    float hnS;
    {
      const int mb = gb >> 4, rb = gb & 15;
      float sih[3], shh[3];
      #pragma unroll
      for (int gam = 0; gam < 3; ++gam) {
        float aih = 0.f, ahh = 0.f;
        #pragma unroll
        for (int q = 0; q < 2; ++q) {
          aih += Cp[(size_t)(((0*2+q)*3+gam)*2 + mb) * 272 + rb * 17 + gj];
          ahh += Cp[(size_t)(((1*2+q)*3+gam)*2 + mb) * 272 + rb * 17 + gj];
        }
        sih[gam] = aih + biasLds[gam * 16 + gj];
        shh[gam] = ahh + biasLds[48 + gam * 16 + gj];
      }
      const float r = sigm_f(sih[0] + shh[0]);
      const float z = sigm_f(sih[1] + shh[1]);
      const float n = tanh_f(sih[2] + r * shh[2]);
      const float hn = (1.f - z) * n + z * hreg;
      hreg = hn;
      hnS = hn;

      const float hother = __shfl_xor(hn, 1);
      if ((gj & 1) == 0) {
        union { unsigned u; _Float16 h[2]; } pr;
        pr.h[0] = f2h(hn); pr.h[1] = f2h(hother);
        unsigned* hp = hexu + ((size_t)dir * 2 + (s & 1)) * (B_SZ * (H_SZ / 2))
                     + (size_t)gb * (H_SZ / 2) + (g * JW + gj) / 2;
        __hip_atomic_store(hp, pr.u, __ATOMIC_RELAXED, __HIP_MEMORY_SCOPE_AGENT);
      }
    }
    // per-wave drain: only this step's h-store (+ long-landed older stores)
    asm volatile("s_waitcnt vmcnt(0)" ::: "memory");
    bar_lgkm();   // B2: every wave has drained its h-store
    if (tid == 0)
      __hip_atomic_store((unsigned*)&flags[(size_t)dir * NWG_DIR + g],
                         (unsigned)(s + 1),
                         __ATOMIC_RELAXED, __HIP_MEMORY_SCOPE_AGENT);

    // ---- off-chain tail: out stores, then issue x(t+1) prefetch
    out[((size_t)gb * T_LEN + t) * (2 * H_SZ) + dir * H_SZ + g * JW + gj] = hnS;
    if (s == T_LEN - 1) hlast[gb * H_SZ + g * JW + gj] = hnS;
    if (!isHh && hasNext) {
      const int tn = dir ? (T_LEN - 2 - s) : (s + 1);
      const float* base = xwavebase + (size_t)tn * D_SZ;
      #pragma unroll
      for (int i = 0; i < 8; ++i) {
        xn[2*i]   = *(const float4*)(base + i * 32);
        xn[2*i+1] = *(const float4*)(base + i * 32 + 4);
      }
    }
  }
}

extern "C" void kernel_launch(void* const* d_in, const int* in_sizes, int n_in,
                              void* d_out, int out_size, void* d_ws, size_t ws_size,
                              hipStream_t stream) {
  const float* x      = (const float*)d_in[0];
  const float* wih_fw = (const float*)d_in[1];
  const float* whh_fw = (const float*)d_in[2];
  const float* bih_fw = (const float*)d_in[3];
  const float* bhh_fw = (const float*)d_in[4];
  const float* wih_bw = (const float*)d_in[5];
  const float* whh_bw = (const float*)d_in[6];
  const float* bih_bw = (const float*)d_in[7];
  const float* bhh_bw = (const float*)d_in[8];
  float* out = (float*)d_out;

  // ws: flags u32[2][32] = 256 B (zeroed per replay, captured in graph);
  //     hexu [2 dir][2 parity][32 rows][256 u32 pairs] = 128 KB (flag-gated).
  const size_t FLAGS_BYTES = 256;
  const size_t HEX_BYTES   = (size_t)2 * 2 * B_SZ * (H_SZ / 2) * sizeof(unsigned);
  if (ws_size < FLAGS_BYTES + HEX_BYTES) return;

  unsigned* flags = (unsigned*)d_ws;
  unsigned* hexu  = (unsigned*)((char*)d_ws + FLAGS_BYTES);

  hipMemsetAsync(flags, 0, FLAGS_BYTES, stream);
  gru2_persistent<<<dim3(64), dim3(NTHR), 0, stream>>>(
      x, wih_fw, whh_fw, bih_fw, bhh_fw, wih_bw, whh_bw, bih_bw, bhh_bw,
      out, hexu, flags);
}